// Round 17
// baseline (172.597 us; speedup 1.0000x reference)
//
#include <hip/hip_runtime.h>

typedef unsigned short u16;
typedef unsigned int u32;
typedef __bf16 bf16x8 __attribute__((ext_vector_type(8)));
typedef float f32x4 __attribute__((ext_vector_type(4)));

#define BB 2
#define TT 2048
#define CC 1024
#define HH 16
#define DD 64
#define MM (BB*TT)   // 4096

__device__ __forceinline__ u16 f2b(float f) {
    union { float f; unsigned int i; } a; a.f = f;
    unsigned int u = a.i;
    unsigned int r = (u + 0x7FFFu + ((u >> 16) & 1u)) >> 16;
    return (u16)r;
}
__device__ __forceinline__ u16 f2b_fast(float f) {
    union { float f; unsigned int i; } a; a.f = f;
    return (u16)((a.i + 0x8000u) >> 16);
}
__device__ __forceinline__ u32 pack2(float lo, float hi) {
    return ((u32)f2b_fast(hi) << 16) | (u32)f2b_fast(lo);
}

// async global -> LDS, 16B per lane (dest must be wave-uniform base + lane*16)
__device__ __forceinline__ void gld16(const u16* g, u16* l) {
    __builtin_amdgcn_global_load_lds(
        (const __attribute__((address_space(1))) unsigned int*)g,
        (__attribute__((address_space(3))) unsigned int*)l, 16, 0, 0);
}

// ---------------- fused preprocessing ----------------
// blocks [0,4096): x fp32 -> bf16. [4096,4864): W_attn transpose.
// [4864,5120): W_proj transpose.
__global__ __launch_bounds__(256) void prep_k(const float* __restrict__ x,
                                              u16* __restrict__ xb,
                                              const float* __restrict__ Wa,
                                              u16* __restrict__ Wat,
                                              const float* __restrict__ Wp,
                                              u16* __restrict__ Wpt) {
    __shared__ u16 tile[64][65];
    const int b = blockIdx.x;
    const int tid = threadIdx.x;
    if (b < 4096) {                       // cvt_x role (block-uniform branch)
        int i = b * 256 + tid;
        float4 v = ((const float4*)x)[i];
        ushort4 o;
        o.x = f2b(v.x); o.y = f2b(v.y); o.z = f2b(v.z); o.w = f2b(v.w);
        ((ushort4*)xb)[i] = o;
        return;
    }
    const float* in; u16* out; int K, N, n0, k0;
    if (b < 4096 + 768) {                 // W_attn transpose role
        int bb = b - 4096;
        in = Wa; out = Wat; K = 1024; N = 3072;
        n0 = (bb % 48) * 64; k0 = (bb / 48) * 64;
    } else {                              // W_proj transpose role
        int bb = b - 4096 - 768;
        in = Wp; out = Wpt; K = 1024; N = 1024;
        n0 = (bb % 16) * 64; k0 = (bb / 16) * 64;
    }
    const int tx = tid & 63, ty = tid >> 6;
    for (int i = 0; i < 16; i++) {
        int row = ty + i * 4;
        tile[row][tx] = f2b(in[(size_t)(k0 + row) * N + n0 + tx]);
    }
    __syncthreads();
    for (int i = 0; i < 16; i++) {
        int row = ty + i * 4;
        out[(size_t)(n0 + row) * K + k0 + tx] = tile[tx][row];
    }
}

// ---------------- GEMM v6 (frozen) ----------------
// All-gld16 staging; LDS XOR-swizzle slot^=((row>>1)&3) both-sides
// (conflicts 3.24M->98K); one barrier/K-step, next step staged right after;
// bijective XCD swizzle. MODE 0: C = [q|k|v], q pre-scaled 0.125*log2e,
// v via in-LDS [128c][136t] transpose -> vt[bh][D][T]. MODE 1: 128x64, fp32 out.
template<int MODE>
__global__ __launch_bounds__(256) void gemm_k(const u16* __restrict__ A,
                                              const u16* __restrict__ Bt,
                                              u16* __restrict__ Cq,
                                              u16* __restrict__ Ck,
                                              u16* __restrict__ Cv,
                                              float* __restrict__ Cout,
                                              int N, int K) {
    constexpr int BN   = (MODE == 0) ? 128 : 64;
    constexpr int NF   = (MODE == 0) ? 4 : 2;
    constexpr int BSU  = BN * 32;                       // Bs u16 per buffer
    constexpr int LDSZ = (MODE == 0) ? (128 * 136) : (2 * 4096 + 2 * BSU);
    __shared__ __attribute__((aligned(16))) u16 smem[LDSZ];
#define AsP(B) (smem + (B) * 4096)
#define BsP(B) (smem + 8192 + (B) * BSU)

    const int tid  = threadIdx.x;
    const int lane = tid & 63, w = tid >> 6;
    const int wm = w >> 1, wn = w & 1;
    const int quad = lane >> 4, l16 = lane & 15;
    const int swg  = (l16 >> 1) & 3;                    // read-side row-swizzle
    const int rsl  = (quad ^ swg) * 8;                  // swizzled 16B-slot (u16 off)

    // XCD-aware bijective swizzle (gridDim.x % 8 == 0)
    const int nwg = gridDim.x, lin = blockIdx.x;
    const int cpx = nwg >> 3;
    const int sw  = (lin & 7) * cpx + (lin >> 3);
    const int ncols = N / BN;
    const int m0 = (sw / ncols) * 128, n0 = (sw % ncols) * BN;

    f32x4 acc[4][NF];
    for (int mi = 0; mi < 4; mi++)
        for (int ni = 0; ni < NF; ni++)
            for (int e = 0; e < 4; e++) acc[mi][ni][e] = 0.f;

#define GSTAGE(BUF, K0) do {                                                  \
    for (int i = 0; i < 2; i++) {                                             \
        int c = tid + 256 * i;                                                \
        int row = c >> 2, sg = c & 3;                                         \
        int g8 = ((sg ^ ((row >> 1) & 3)) * 8);                               \
        if constexpr (MODE == 0) {                                            \
            gld16(A + (size_t)(m0 + row) * K + (K0) + g8, AsP(BUF) + c * 8);  \
        } else {                                                              \
            int m = m0 + row;                                                 \
            int b = m >> 11, t = m & 2047;                                    \
            int kk = (K0) + g8;                                               \
            int h = kk >> 6, d = kk & 63;                                     \
            gld16(A + ((size_t)(b * HH + h) * TT + t) * DD + d,               \
                  AsP(BUF) + c * 8);                                          \
        }                                                                     \
    }                                                                         \
    if constexpr (MODE == 0) {                                                \
        for (int i = 0; i < 2; i++) {                                         \
            int c = tid + 256 * i;                                            \
            int row = c >> 2;                                                 \
            int g = (c & 3) ^ ((row >> 1) & 3);                               \
            gld16(Bt + (size_t)(n0 + row) * K + (K0) + g * 8,                 \
                  BsP(BUF) + c * 8);                                          \
        }                                                                     \
    } else {                                                                  \
        int row = tid >> 2;                                                   \
        int g = (tid & 3) ^ ((row >> 1) & 3);                                 \
        gld16(Bt + (size_t)(n0 + row) * K + (K0) + g * 8,                     \
              BsP(BUF) + tid * 8);                                            \
    }                                                                         \
} while (0)

    GSTAGE(0, 0);                         // prologue: stage K-step 0
    const int nk = K >> 5;
    for (int jk = 0; jk < nk; jk++) {
        const int cb = jk & 1;
        __syncthreads();                  // stage(jk) visible; buf cb^1 free
        if (jk + 1 < nk) { GSTAGE(cb ^ 1, (jk + 1) * 32); }
        bf16x8 af[4], bfm[NF];
        for (int mi = 0; mi < 4; mi++)
            af[mi] = *(const bf16x8*)(AsP(cb) + (wm * 64 + mi * 16 + l16) * 32 + rsl);
        for (int ni = 0; ni < NF; ni++)
            bfm[ni] = *(const bf16x8*)(BsP(cb) + ((BN / 2) * wn + ni * 16 + l16) * 32 + rsl);
        for (int mi = 0; mi < 4; mi++)
            for (int ni = 0; ni < NF; ni++)
                acc[mi][ni] = __builtin_amdgcn_mfma_f32_16x16x32_bf16(
                    af[mi], bfm[ni], acc[mi][ni], 0, 0, 0);
    }
#undef GSTAGE

    if constexpr (MODE == 0) {
        const float SCQ = 0.125f * 1.44269504f;
        const int which = n0 >> 10;                 // block-uniform (n0 % 128 == 0)
        if (which < 2) {                            // q / k: scatter to [bh][T][D]
            for (int mi = 0; mi < 4; mi++)
                for (int ni = 0; ni < 4; ni++)
                    for (int r = 0; r < 4; r++) {
                        int row = m0 + wm * 64 + mi * 16 + quad * 4 + r;
                        int col = n0 + wn * 64 + ni * 16 + l16;
                        int h = (col >> 6) & 15, d = col & 63;
                        int b = row >> 11, t = row & 2047;
                        size_t off = ((size_t)(b * HH + h) * TT + t) * DD + d;
                        float val = acc[mi][ni][r];
                        if (which == 0) val *= SCQ;
                        (which == 0 ? Cq : Ck)[off] = f2b(val);
                    }
        } else {                                    // v: LDS-transpose -> vt[bh][D][T]
            __syncthreads();                        // staging buffers now dead
            for (int mi = 0; mi < 4; mi++)
                for (int ni = 0; ni < 4; ni++)
                    for (int r = 0; r < 4; r++) {
                        int cl = wn * 64 + ni * 16 + l16;
                        int tl = wm * 64 + mi * 16 + quad * 4 + r;
                        smem[cl * 136 + tl] = f2b(acc[mi][ni][r]);
                    }
            __syncthreads();
            const int b = m0 >> 11, t0l = m0 & 2047;
            const int c0 = n0 - 2048;
            for (int j = 0; j < 8; j++) {
                int idx = j * 256 + tid;
                int cl = idx >> 4, ch = idx & 15;
                int cg = c0 + cl, h = cg >> 6, d = cg & 63;
                uint4 val = *(const uint4*)&smem[cl * 136 + ch * 8];
                *(uint4*)&Cv[((size_t)(b * HH + h) * DD + d) * TT + t0l + ch * 8] = val;
            }
        }
    } else {
        for (int mi = 0; mi < 4; mi++)
            for (int ni = 0; ni < NF; ni++)
                for (int r = 0; r < 4; r++) {
                    int row = m0 + wm * 64 + mi * 16 + quad * 4 + r;
                    int col = n0 + wn * 32 + ni * 16 + l16;
                    Cout[(size_t)row * N + col] = acc[mi][ni][r];
                }
    }
#undef AsP
#undef BsP
}

// ---------------- flash attention v14: paired subtiles, uniform 17 units/block ----------------
// R16 analysis: v13's 1024 blocks have work 1..16 passes; all are resident from
// t=0, so the 64 work-16 blocks define a ~7-pass tail on 64/256 CUs (~20% of
// attn). v14: block (bh,p) owns subtiles {31-p, p} -> nkt0+nkt1 = 17 UNIFORM.
// K/V tiles staged ONCE per jk serve BOTH subtiles during the overlap phase
// (stagings 8704 -> 6400, and per-staged-tile compute doubles = better cover).
// 512 blocks = 2 blocks/CU (occupancy counter will read lower; the tail and
// staging wins are the bet). All v13 machinery kept: swapped QK^T (in-register
// P, no Ps), fixed-max softmax, single-buffered K/V 32 KB, 2 barriers/pass,
// XOR swizzle both-sides, XCD = bh%8.
__global__ __launch_bounds__(256, 2) void attn_k(const u16* __restrict__ Q,
                                                 const u16* __restrict__ Kb,
                                                 const u16* __restrict__ Vtg,
                                                 u16* __restrict__ Y) {
    __shared__ __attribute__((aligned(16))) u16 Ks[128 * 64];   // 16 KB
    __shared__ __attribute__((aligned(16))) u16 Vs[64 * 128];   // 16 KB
    const int tid  = threadIdx.x;
    const int lane = tid & 63, w = tid >> 6;
    const int quad = lane >> 4, l16 = lane & 15;
    const int bh = blockIdx.x;                 // 0..31 -> XCD = bh%8
    const int p  = blockIdx.y;                 // 0..15
    const int sb0 = 31 - p, sb1 = p;
    const int nkt0 = (sb0 >> 1) + 1;           // 9..16
    const int nkt1 = (sb1 >> 1) + 1;           // 1..8  (nkt0+nkt1 = 17)
    const size_t base  = (size_t)bh * TT * DD;
    const size_t baseV = (size_t)bh * DD * TT;

    // per-lane staging offsets: 4 rounds x 256 lanes cover 1024 16B-slots/tile.
    // content swizzle: LDS slot s of row holds global col-group s^(row&7).
    int ksidx[4], koff[4], voff[4];
    for (int r = 0; r < 4; r++) {
        int sidx = r * 256 + tid;
        ksidx[r] = sidx;
        int kr = sidx >> 3, ksl = sidx & 7;
        koff[r] = kr * 64 + ((ksl ^ (kr & 7)) << 3);
        int vr = sidx >> 4, vsl = sidx & 15;
        voff[r] = vr * TT + ((vsl ^ (vr & 7)) << 3);
    }
    const u16* kg = Kb + base;      // + jk*8192 + koff[r]
    const u16* vg = Vtg + baseV;    // + jk*128  + voff[r]

    // prologue: stage tile 0
    for (int r = 0; r < 4; r++) gld16(kg + koff[r], &Ks[ksidx[r] * 8]);
    for (int r = 0; r < 4; r++) gld16(vg + voff[r], &Vs[ksidx[r] * 8]);

    // Q fragments for both subtiles (B-operand: q on l16, d on quad)
    bf16x8 qf0[2], qf1[2];
    for (int kk = 0; kk < 2; kk++) {
        qf0[kk] = *(const bf16x8*)(Q + base +
            (size_t)(sb0 * 64 + w * 16 + l16) * DD + kk * 32 + quad * 8);
        qf1[kk] = *(const bf16x8*)(Q + base +
            (size_t)(sb1 * 64 + w * 16 + l16) * DD + kk * 32 + quad * 8);
    }

    // ds_read swizzled slot offsets (u16 elements)
    const int swx = (l16 & 7);
    const int swk0 = ((quad ^ swx) << 3);
    const int swk1 = (((4 + quad) ^ swx) << 3);

    const int qr   = w * 16 + l16;             // q row within subtile
    const int srcA = ((quad & 1) << 5) + l16;  // shfl source: quad_s = 2*(quad&1)
    const int hi   = quad >> 1;

    float lsum0 = 0.f, lsum1 = 0.f;
    f32x4 oacc0[4], oacc1[4];
    for (int nd = 0; nd < 4; nd++)
        for (int e = 0; e < 4; e++) { oacc0[nd][e] = 0.f; oacc1[nd][e] = 0.f; }

    // one subtile-unit: QK^T (swapped) + fixed-max softmax + PV, all v13-style
#define UNIT(QF, OACC, LSUM, SB) do {                                         \
    f32x4 sT[8];                                                              \
    for (int ni = 0; ni < 8; ni++)                                            \
        for (int e = 0; e < 4; e++) sT[ni][e] = 0.f;                          \
    {                                                                         \
        bf16x8 kfa[8];                                                        \
        for (int ni = 0; ni < 8; ni++)                                        \
            kfa[ni] = *(const bf16x8*)&Ks[(ni * 16 + l16) * 64 + swk0];       \
        for (int ni = 0; ni < 8; ni++)                                        \
            sT[ni] = __builtin_amdgcn_mfma_f32_16x16x32_bf16(                 \
                kfa[ni], QF[0], sT[ni], 0, 0, 0);                             \
    }                                                                         \
    {                                                                         \
        bf16x8 kfa[8];                                                        \
        for (int ni = 0; ni < 8; ni++)                                        \
            kfa[ni] = *(const bf16x8*)&Ks[(ni * 16 + l16) * 64 + swk1];       \
        for (int ni = 0; ni < 8; ni++)                                        \
            sT[ni] = __builtin_amdgcn_mfma_f32_16x16x32_bf16(                 \
                kfa[ni], QF[1], sT[ni], 0, 0, 0);                             \
    }                                                                         \
    if (jk == ((SB) >> 1)) {               /* diagonal: k > q -> -inf */      \
        int kb0 = jk * 128 + quad * 4;                                        \
        int qgl = (SB) * 64 + qr;                                             \
        for (int ni = 0; ni < 8; ni++)                                        \
            for (int r = 0; r < 4; r++)                                       \
                if (kb0 + ni * 16 + r > qgl) sT[ni][r] = -1e30f;              \
    }                                                                         \
    u32 pd[8][2];                                                             \
    for (int ni = 0; ni < 8; ni++) {                                          \
        float p0 = __builtin_amdgcn_exp2f(sT[ni][0]);                         \
        float p1 = __builtin_amdgcn_exp2f(sT[ni][1]);                         \
        float p2 = __builtin_amdgcn_exp2f(sT[ni][2]);                         \
        float p3 = __builtin_amdgcn_exp2f(sT[ni][3]);                         \
        LSUM += (p0 + p1) + (p2 + p3);                                        \
        pd[ni][0] = pack2(p0, p1);                                            \
        pd[ni][1] = pack2(p2, p3);                                            \
    }                                                                         \
    for (int kk = 0; kk < 4; kk++) {                                          \
        const int swv = (((kk * 4 + quad) ^ swx) << 3);                       \
        bf16x8 vfa[4];                                                        \
        for (int nd = 0; nd < 4; nd++)                                        \
            vfa[nd] = *(const bf16x8*)&Vs[(nd * 16 + l16) * 128 + swv];       \
        u32 a0 = pd[2 * kk][0],     a1 = pd[2 * kk][1];                       \
        u32 b0 = pd[2 * kk + 1][0], b1 = pd[2 * kk + 1][1];                   \
        u32 t0 = __shfl((int)a0, srcA),      t1 = __shfl((int)a1, srcA);      \
        u32 t2 = __shfl((int)a0, srcA + 16), t3 = __shfl((int)a1, srcA + 16); \
        u32 u0 = __shfl((int)b0, srcA),      u1 = __shfl((int)b1, srcA);      \
        u32 u2 = __shfl((int)b0, srcA + 16), u3 = __shfl((int)b1, srcA + 16); \
        union { u32 d[4]; bf16x8 v; } pf;                                     \
        pf.d[0] = hi ? u0 : t0;                                               \
        pf.d[1] = hi ? u1 : t1;                                               \
        pf.d[2] = hi ? u2 : t2;                                               \
        pf.d[3] = hi ? u3 : t3;                                               \
        for (int nd = 0; nd < 4; nd++)                                        \
            OACC[nd] = __builtin_amdgcn_mfma_f32_16x16x32_bf16(               \
                pf.v, vfa[nd], OACC[nd], 0, 0, 0);                            \
    }                                                                         \
} while (0)

    for (int jk = 0; jk < nkt0; jk++) {
        __syncthreads();   // B1: stage(jk) visible (drains the gld16s)

        UNIT(qf0, oacc0, lsum0, sb0);
        if (jk < nkt1) UNIT(qf1, oacc1, lsum1, sb1);

        // ---- B2: all reads done -> stage jk+1 into the same buffers ----
        if (jk + 1 < nkt0) {
            __syncthreads();
            const u16* kn = kg + (size_t)(jk + 1) * (128 * DD);
            const u16* vn = vg + (size_t)(jk + 1) * 128;
            for (int r = 0; r < 4; r++)
                gld16(kn + koff[r], &Ks[ksidx[r] * 8]);
            for (int r = 0; r < 4; r++)
                gld16(vn + voff[r], &Vs[ksidx[r] * 8]);
        }
    }
#undef UNIT

    // reduce lsums across quads, redistribute for the Y divide
    lsum0 += __shfl_xor(lsum0, 16);
    lsum0 += __shfl_xor(lsum0, 32);
    lsum1 += __shfl_xor(lsum1, 16);
    lsum1 += __shfl_xor(lsum1, 32);
    float lsty0[4], lsty1[4];
    for (int r = 0; r < 4; r++) {
        lsty0[r] = __shfl(lsum0, quad * 4 + r);
        lsty1[r] = __shfl(lsum1, quad * 4 + r);
    }

    for (int nd = 0; nd < 4; nd++)
        for (int r = 0; r < 4; r++) {
            int rr = w * 16 + quad * 4 + r;
            int col = nd * 16 + l16;
            Y[base + (size_t)(sb0 * 64 + rr) * DD + col] = f2b(oacc0[nd][r] / lsty0[r]);
            Y[base + (size_t)(sb1 * 64 + rr) * DD + col] = f2b(oacc1[nd][r] / lsty1[r]);
        }
}

extern "C" void kernel_launch(void* const* d_in, const int* in_sizes, int n_in,
                              void* d_out, int out_size, void* d_ws, size_t ws_size,
                              hipStream_t stream) {
    const float* x      = (const float*)d_in[0];   // [2,2048,1024] fp32
    const float* W_attn = (const float*)d_in[1];   // [1024,3072]  fp32
    const float* W_proj = (const float*)d_in[2];   // [1024,1024]  fp32
    float* out = (float*)d_out;                    // [2,2048,1024] fp32

    u16* Wt_attn = (u16*)d_ws;                    // 3072*1024
    u16* Wt_proj = Wt_attn + 3072 * 1024;         // 1024*1024
    u16* xb      = Wt_proj + 1024 * 1024;         // 4096*1024 bf16 x
    u16* q       = xb + (size_t)MM * CC;
    u16* k       = q + (size_t)32 * 2048 * 64;
    u16* vt      = k + (size_t)32 * 2048 * 64;    // [bh][D][T], written by gemm0
    u16* y       = vt + (size_t)32 * 2048 * 64;

    // 4 launches: prep (x-cvt + weights) -> gemm0 (all-gld16) -> attn -> gemm1
    prep_k<<<dim3(4096 + 768 + 256), 256, 0, stream>>>(
        x, xb, W_attn, Wt_attn, W_proj, Wt_proj);
    gemm_k<0><<<dim3((MM / 128) * (3072 / 128)), 256, 0, stream>>>(
        xb, Wt_attn, q, k, vt, nullptr, 3072, 1024);
    attn_k<<<dim3(32, 16), 256, 0, stream>>>(q, k, vt, y);
    gemm_k<1><<<dim3((MM / 128) * (1024 / 64)), 256, 0, stream>>>(
        y, Wt_proj, nullptr, nullptr, nullptr, out, 1024, 1024);
}

// Round 18
// 167.867 us; speedup vs baseline: 1.0282x; 1.0282x over previous
//
#include <hip/hip_runtime.h>

typedef unsigned short u16;
typedef unsigned int u32;
typedef __bf16 bf16x8 __attribute__((ext_vector_type(8)));
typedef float f32x4 __attribute__((ext_vector_type(4)));

#define BB 2
#define TT 2048
#define CC 1024
#define HH 16
#define DD 64
#define MM (BB*TT)   // 4096

__device__ __forceinline__ u16 f2b(float f) {
    union { float f; unsigned int i; } a; a.f = f;
    unsigned int u = a.i;
    unsigned int r = (u + 0x7FFFu + ((u >> 16) & 1u)) >> 16;
    return (u16)r;
}
__device__ __forceinline__ u16 f2b_fast(float f) {
    union { float f; unsigned int i; } a; a.f = f;
    return (u16)((a.i + 0x8000u) >> 16);
}
__device__ __forceinline__ u32 pack2(float lo, float hi) {
    return ((u32)f2b_fast(hi) << 16) | (u32)f2b_fast(lo);
}

// async global -> LDS, 16B per lane (dest must be wave-uniform base + lane*16)
__device__ __forceinline__ void gld16(const u16* g, u16* l) {
    __builtin_amdgcn_global_load_lds(
        (const __attribute__((address_space(1))) unsigned int*)g,
        (__attribute__((address_space(3))) unsigned int*)l, 16, 0, 0);
}

// ---------------- fused preprocessing ----------------
// blocks [0,4096): x fp32 -> bf16. [4096,4864): W_attn transpose.
// [4864,5120): W_proj transpose.
__global__ __launch_bounds__(256) void prep_k(const float* __restrict__ x,
                                              u16* __restrict__ xb,
                                              const float* __restrict__ Wa,
                                              u16* __restrict__ Wat,
                                              const float* __restrict__ Wp,
                                              u16* __restrict__ Wpt) {
    __shared__ u16 tile[64][65];
    const int b = blockIdx.x;
    const int tid = threadIdx.x;
    if (b < 4096) {                       // cvt_x role (block-uniform branch)
        int i = b * 256 + tid;
        float4 v = ((const float4*)x)[i];
        ushort4 o;
        o.x = f2b(v.x); o.y = f2b(v.y); o.z = f2b(v.z); o.w = f2b(v.w);
        ((ushort4*)xb)[i] = o;
        return;
    }
    const float* in; u16* out; int K, N, n0, k0;
    if (b < 4096 + 768) {                 // W_attn transpose role
        int bb = b - 4096;
        in = Wa; out = Wat; K = 1024; N = 3072;
        n0 = (bb % 48) * 64; k0 = (bb / 48) * 64;
    } else {                              // W_proj transpose role
        int bb = b - 4096 - 768;
        in = Wp; out = Wpt; K = 1024; N = 1024;
        n0 = (bb % 16) * 64; k0 = (bb / 16) * 64;
    }
    const int tx = tid & 63, ty = tid >> 6;
    for (int i = 0; i < 16; i++) {
        int row = ty + i * 4;
        tile[row][tx] = f2b(in[(size_t)(k0 + row) * N + n0 + tx]);
    }
    __syncthreads();
    for (int i = 0; i < 16; i++) {
        int row = ty + i * 4;
        out[(size_t)(n0 + row) * K + k0 + tx] = tile[tx][row];
    }
}

// ---------------- GEMM v7: v6 + m-major-within-XCD-chunk (B-panel L2-resident) ----------------
// v6's n-major chunk gave each XCD all N columns -> B-panel = 6 MB > 4 MB L2
// (FETCH 32.8 MB vs ~14 ideal). v7: m-major within chunk -> per-XCD B-panel =
// ncols/8 * 128 cols (~1 MB MODE0, ~256 KB MODE1) stays L2-resident; A streams.
// Rest frozen: all-gld16 staging, LDS XOR-swizzle slot^=((row>>1)&3) both-sides
// (conflicts 98K), one barrier/K-step with next staged right after, bijective
// XCD chunking. MODE 0: C = [q|k|v], q pre-scaled 0.125*log2e, v via in-LDS
// [128c][136t] transpose -> vt[bh][D][T]. MODE 1: 128x64 tile, fp32 out.
template<int MODE>
__global__ __launch_bounds__(256) void gemm_k(const u16* __restrict__ A,
                                              const u16* __restrict__ Bt,
                                              u16* __restrict__ Cq,
                                              u16* __restrict__ Ck,
                                              u16* __restrict__ Cv,
                                              float* __restrict__ Cout,
                                              int N, int K) {
    constexpr int BN   = (MODE == 0) ? 128 : 64;
    constexpr int NF   = (MODE == 0) ? 4 : 2;
    constexpr int BSU  = BN * 32;                       // Bs u16 per buffer
    constexpr int LDSZ = (MODE == 0) ? (128 * 136) : (2 * 4096 + 2 * BSU);
    __shared__ __attribute__((aligned(16))) u16 smem[LDSZ];
#define AsP(B) (smem + (B) * 4096)
#define BsP(B) (smem + 8192 + (B) * BSU)

    const int tid  = threadIdx.x;
    const int lane = tid & 63, w = tid >> 6;
    const int wm = w >> 1, wn = w & 1;
    const int quad = lane >> 4, l16 = lane & 15;
    const int swg  = (l16 >> 1) & 3;                    // read-side row-swizzle
    const int rsl  = (quad ^ swg) * 8;                  // swizzled 16B-slot (u16 off)

    // XCD-aware bijective swizzle (gridDim.x % 8 == 0), m-major within chunk
    const int nwg = gridDim.x, lin = blockIdx.x;
    const int cpx = nwg >> 3;
    const int sw  = (lin & 7) * cpx + (lin >> 3);
    const int nrows = MM / 128;                         // 32
    const int m0 = (sw % nrows) * 128, n0 = (sw / nrows) * BN;

    f32x4 acc[4][NF];
    for (int mi = 0; mi < 4; mi++)
        for (int ni = 0; ni < NF; ni++)
            for (int e = 0; e < 4; e++) acc[mi][ni][e] = 0.f;

#define GSTAGE(BUF, K0) do {                                                  \
    for (int i = 0; i < 2; i++) {                                             \
        int c = tid + 256 * i;                                                \
        int row = c >> 2, sg = c & 3;                                         \
        int g8 = ((sg ^ ((row >> 1) & 3)) * 8);                               \
        if constexpr (MODE == 0) {                                            \
            gld16(A + (size_t)(m0 + row) * K + (K0) + g8, AsP(BUF) + c * 8);  \
        } else {                                                              \
            int m = m0 + row;                                                 \
            int b = m >> 11, t = m & 2047;                                    \
            int kk = (K0) + g8;                                               \
            int h = kk >> 6, d = kk & 63;                                     \
            gld16(A + ((size_t)(b * HH + h) * TT + t) * DD + d,               \
                  AsP(BUF) + c * 8);                                          \
        }                                                                     \
    }                                                                         \
    if constexpr (MODE == 0) {                                                \
        for (int i = 0; i < 2; i++) {                                         \
            int c = tid + 256 * i;                                            \
            int row = c >> 2;                                                 \
            int g = (c & 3) ^ ((row >> 1) & 3);                               \
            gld16(Bt + (size_t)(n0 + row) * K + (K0) + g * 8,                 \
                  BsP(BUF) + c * 8);                                          \
        }                                                                     \
    } else {                                                                  \
        int row = tid >> 2;                                                   \
        int g = (tid & 3) ^ ((row >> 1) & 3);                                 \
        gld16(Bt + (size_t)(n0 + row) * K + (K0) + g * 8,                     \
              BsP(BUF) + tid * 8);                                            \
    }                                                                         \
} while (0)

    GSTAGE(0, 0);                         // prologue: stage K-step 0
    const int nk = K >> 5;
    for (int jk = 0; jk < nk; jk++) {
        const int cb = jk & 1;
        __syncthreads();                  // stage(jk) visible; buf cb^1 free
        if (jk + 1 < nk) { GSTAGE(cb ^ 1, (jk + 1) * 32); }
        bf16x8 af[4], bfm[NF];
        for (int mi = 0; mi < 4; mi++)
            af[mi] = *(const bf16x8*)(AsP(cb) + (wm * 64 + mi * 16 + l16) * 32 + rsl);
        for (int ni = 0; ni < NF; ni++)
            bfm[ni] = *(const bf16x8*)(BsP(cb) + ((BN / 2) * wn + ni * 16 + l16) * 32 + rsl);
        for (int mi = 0; mi < 4; mi++)
            for (int ni = 0; ni < NF; ni++)
                acc[mi][ni] = __builtin_amdgcn_mfma_f32_16x16x32_bf16(
                    af[mi], bfm[ni], acc[mi][ni], 0, 0, 0);
    }
#undef GSTAGE

    if constexpr (MODE == 0) {
        const float SCQ = 0.125f * 1.44269504f;
        const int which = n0 >> 10;                 // block-uniform (n0 % 128 == 0)
        if (which < 2) {                            // q / k: scatter to [bh][T][D]
            for (int mi = 0; mi < 4; mi++)
                for (int ni = 0; ni < 4; ni++)
                    for (int r = 0; r < 4; r++) {
                        int row = m0 + wm * 64 + mi * 16 + quad * 4 + r;
                        int col = n0 + wn * 64 + ni * 16 + l16;
                        int h = (col >> 6) & 15, d = col & 63;
                        int b = row >> 11, t = row & 2047;
                        size_t off = ((size_t)(b * HH + h) * TT + t) * DD + d;
                        float val = acc[mi][ni][r];
                        if (which == 0) val *= SCQ;
                        (which == 0 ? Cq : Ck)[off] = f2b(val);
                    }
        } else {                                    // v: LDS-transpose -> vt[bh][D][T]
            __syncthreads();                        // staging buffers now dead
            for (int mi = 0; mi < 4; mi++)
                for (int ni = 0; ni < 4; ni++)
                    for (int r = 0; r < 4; r++) {
                        int cl = wn * 64 + ni * 16 + l16;
                        int tl = wm * 64 + mi * 16 + quad * 4 + r;
                        smem[cl * 136 + tl] = f2b(acc[mi][ni][r]);
                    }
            __syncthreads();
            const int b = m0 >> 11, t0l = m0 & 2047;
            const int c0 = n0 - 2048;
            for (int j = 0; j < 8; j++) {
                int idx = j * 256 + tid;
                int cl = idx >> 4, ch = idx & 15;
                int cg = c0 + cl, h = cg >> 6, d = cg & 63;
                uint4 val = *(const uint4*)&smem[cl * 136 + ch * 8];
                *(uint4*)&Cv[((size_t)(b * HH + h) * DD + d) * TT + t0l + ch * 8] = val;
            }
        }
    } else {
        for (int mi = 0; mi < 4; mi++)
            for (int ni = 0; ni < NF; ni++)
                for (int r = 0; r < 4; r++) {
                    int row = m0 + wm * 64 + mi * 16 + quad * 4 + r;
                    int col = n0 + wn * 32 + ni * 16 + l16;
                    Cout[(size_t)row * N + col] = acc[mi][ni][r];
                }
    }
#undef AsP
#undef BsP
}

// ---------------- flash attention v13 (REVERTED from v14; measured 43.9 us R16) ----------------
// R17 lesson: paired-subtile v14 halved residency (occ 31->17%) and LOST (+3 us)
// -- v13's per-CU work sums were already balanced; the wave-decay tail is
// cheaper than losing 2 blocks/CU. v13: swapped QK^T (in-register P, no Ps),
// fixed-max softmax (M=0, log2 domain), single-buffered K/V 32 KB, 2 barriers/
// pass, XOR swizzle both-sides, grid (bh=32, y=32), causal-balanced, XCD=bh%8.
__global__ __launch_bounds__(256, 2) void attn_k(const u16* __restrict__ Q,
                                                 const u16* __restrict__ Kb,
                                                 const u16* __restrict__ Vtg,
                                                 u16* __restrict__ Y) {
    __shared__ __attribute__((aligned(16))) u16 Ks[128 * 64];   // 16 KB
    __shared__ __attribute__((aligned(16))) u16 Vs[64 * 128];   // 16 KB
    const int tid  = threadIdx.x;
    const int lane = tid & 63, w = tid >> 6;
    const int quad = lane >> 4, l16 = lane & 15;
    const int bh = blockIdx.x;                 // 0..31 -> XCD = bh%8
    const int y  = blockIdx.y;                 // 0..31
    // work table balances causal load: work = nkt = (sb>>1)+1
    const int rowi = (y >> 1) & 3, coli = y >> 3;
    const int basew = ((coli & 1) ? 9 : 16) - ((coli >> 1) << 3);
    const int work = basew + ((coli & 1) ? rowi : -rowi);
    const int sb = 2 * (work - 1) + (y & 1);
    const int nkt = work;
    const size_t base  = (size_t)bh * TT * DD;
    const size_t baseV = (size_t)bh * DD * TT;

    // per-lane staging offsets: 4 rounds x 256 lanes cover 1024 16B-slots/tile.
    // content swizzle: LDS slot s of row holds global col-group s^(row&7).
    int ksidx[4], koff[4], voff[4];
    for (int r = 0; r < 4; r++) {
        int sidx = r * 256 + tid;
        ksidx[r] = sidx;
        int kr = sidx >> 3, ksl = sidx & 7;
        koff[r] = kr * 64 + ((ksl ^ (kr & 7)) << 3);
        int vr = sidx >> 4, vsl = sidx & 15;
        voff[r] = vr * TT + ((vsl ^ (vr & 7)) << 3);
    }
    const u16* kg = Kb + base;      // + jk*8192 + koff[r]
    const u16* vg = Vtg + baseV;    // + jk*128  + voff[r]

    // prologue: stage tile 0
    for (int r = 0; r < 4; r++) gld16(kg + koff[r], &Ks[ksidx[r] * 8]);
    for (int r = 0; r < 4; r++) gld16(vg + voff[r], &Vs[ksidx[r] * 8]);

    // Q fragments (B-operand: q on l16, d on quad)
    bf16x8 qf[2];
    for (int kk = 0; kk < 2; kk++)
        qf[kk] = *(const bf16x8*)(Q + base +
            (size_t)(sb * 64 + w * 16 + l16) * DD + kk * 32 + quad * 8);

    // ds_read swizzled slot offsets (u16 elements)
    const int swx = (l16 & 7);
    const int swk0 = ((quad ^ swx) << 3);
    const int swk1 = (((4 + quad) ^ swx) << 3);

    const int qg   = sb * 64 + w * 16 + l16;   // this lane's q row (global)
    const int srcA = ((quad & 1) << 5) + l16;  // shfl source: quad_s = 2*(quad&1)
    const int hi   = quad >> 1;

    float lsum = 0.f;                          // lane-local P row-sum (q = l16)
    f32x4 oacc[4];
    for (int nd = 0; nd < 4; nd++)
        for (int e = 0; e < 4; e++) oacc[nd][e] = 0.f;

    for (int jk = 0; jk < nkt; jk++) {
        __syncthreads();   // B1: stage(jk) visible (drains the gld16s)

        // ---- S^T = K Q^T from LDS: sT[ni] holds S^T[k=ni*16+quad*4+r][q=l16] ----
        f32x4 sT[8];
        for (int ni = 0; ni < 8; ni++)
            for (int e = 0; e < 4; e++) sT[ni][e] = 0.f;
        {
            bf16x8 kfa[8];
            for (int ni = 0; ni < 8; ni++)
                kfa[ni] = *(const bf16x8*)&Ks[(ni * 16 + l16) * 64 + swk0];
            for (int ni = 0; ni < 8; ni++)
                sT[ni] = __builtin_amdgcn_mfma_f32_16x16x32_bf16(
                    kfa[ni], qf[0], sT[ni], 0, 0, 0);
        }
        {
            bf16x8 kfa[8];
            for (int ni = 0; ni < 8; ni++)
                kfa[ni] = *(const bf16x8*)&Ks[(ni * 16 + l16) * 64 + swk1];
            for (int ni = 0; ni < 8; ni++)
                sT[ni] = __builtin_amdgcn_mfma_f32_16x16x32_bf16(
                    kfa[ni], qf[1], sT[ni], 0, 0, 0);
        }

        // ---- causal mask (diagonal tile): k > q -> -inf ----
        if (jk == (sb >> 1)) {
            int kb0 = jk * 128 + quad * 4;
            for (int ni = 0; ni < 8; ni++)
                for (int r = 0; r < 4; r++)
                    if (kb0 + ni * 16 + r > qg) sT[ni][r] = -1e30f;
        }

        // ---- fixed-max softmax (M=0) + bf16 pack, all in-register ----
        u32 pd[8][2];
        for (int ni = 0; ni < 8; ni++) {
            float p0 = __builtin_amdgcn_exp2f(sT[ni][0]);
            float p1 = __builtin_amdgcn_exp2f(sT[ni][1]);
            float p2 = __builtin_amdgcn_exp2f(sT[ni][2]);
            float p3 = __builtin_amdgcn_exp2f(sT[ni][3]);
            lsum += (p0 + p1) + (p2 + p3);
            pd[ni][0] = pack2(p0, p1);
            pd[ni][1] = pack2(p2, p3);
        }

        // ---- O += P V: pf assembled from pd via 8 shfl per kk ----
        for (int kk = 0; kk < 4; kk++) {
            const int swv = (((kk * 4 + quad) ^ swx) << 3);
            bf16x8 vfa[4];
            for (int nd = 0; nd < 4; nd++)
                vfa[nd] = *(const bf16x8*)&Vs[(nd * 16 + l16) * 128 + swv];
            u32 a0 = pd[2 * kk][0],     a1 = pd[2 * kk][1];
            u32 b0 = pd[2 * kk + 1][0], b1 = pd[2 * kk + 1][1];
            u32 t0 = __shfl((int)a0, srcA),      t1 = __shfl((int)a1, srcA);
            u32 t2 = __shfl((int)a0, srcA + 16), t3 = __shfl((int)a1, srcA + 16);
            u32 u0 = __shfl((int)b0, srcA),      u1 = __shfl((int)b1, srcA);
            u32 u2 = __shfl((int)b0, srcA + 16), u3 = __shfl((int)b1, srcA + 16);
            union { u32 d[4]; bf16x8 v; } pf;
            pf.d[0] = hi ? u0 : t0;
            pf.d[1] = hi ? u1 : t1;
            pf.d[2] = hi ? u2 : t2;
            pf.d[3] = hi ? u3 : t3;
            for (int nd = 0; nd < 4; nd++)
                oacc[nd] = __builtin_amdgcn_mfma_f32_16x16x32_bf16(
                    pf.v, vfa[nd], oacc[nd], 0, 0, 0);
        }

        // ---- B2: all reads done -> stage jk+1 into the same buffers ----
        if (jk + 1 < nkt) {
            __syncthreads();
            const u16* kn = kg + (size_t)(jk + 1) * (128 * DD);
            const u16* vn = vg + (size_t)(jk + 1) * 128;
            for (int r = 0; r < 4; r++)
                gld16(kn + koff[r], &Ks[ksidx[r] * 8]);
            for (int r = 0; r < 4; r++)
                gld16(vn + voff[r], &Vs[ksidx[r] * 8]);
        }
    }

    // reduce lsum across quads (lanes sharing l16 hold the 4 k-slices of q=l16)
    lsum += __shfl_xor(lsum, 16);
    lsum += __shfl_xor(lsum, 32);
    // redistribute: Y-write lane needs the sum for q = quad*4+r (held at l16=q)
    float lsty[4];
    for (int r = 0; r < 4; r++)
        lsty[r] = __shfl(lsum, quad * 4 + r);

    for (int nd = 0; nd < 4; nd++)
        for (int r = 0; r < 4; r++) {
            int row = sb * 64 + w * 16 + quad * 4 + r;
            int col = nd * 16 + l16;
            Y[base + (size_t)row * DD + col] = f2b(oacc[nd][r] / lsty[r]);
        }
}

extern "C" void kernel_launch(void* const* d_in, const int* in_sizes, int n_in,
                              void* d_out, int out_size, void* d_ws, size_t ws_size,
                              hipStream_t stream) {
    const float* x      = (const float*)d_in[0];   // [2,2048,1024] fp32
    const float* W_attn = (const float*)d_in[1];   // [1024,3072]  fp32
    const float* W_proj = (const float*)d_in[2];   // [1024,1024]  fp32
    float* out = (float*)d_out;                    // [2,2048,1024] fp32

    u16* Wt_attn = (u16*)d_ws;                    // 3072*1024
    u16* Wt_proj = Wt_attn + 3072 * 1024;         // 1024*1024
    u16* xb      = Wt_proj + 1024 * 1024;         // 4096*1024 bf16 x
    u16* q       = xb + (size_t)MM * CC;
    u16* k       = q + (size_t)32 * 2048 * 64;
    u16* vt      = k + (size_t)32 * 2048 * 64;    // [bh][D][T], written by gemm0
    u16* y       = vt + (size_t)32 * 2048 * 64;

    // 4 launches: prep (x-cvt + weights) -> gemm0 (all-gld16) -> attn -> gemm1
    prep_k<<<dim3(4096 + 768 + 256), 256, 0, stream>>>(
        x, xb, W_attn, Wt_attn, W_proj, Wt_proj);
    gemm_k<0><<<dim3((MM / 128) * (3072 / 128)), 256, 0, stream>>>(
        xb, Wt_attn, q, k, vt, nullptr, 3072, 1024);
    attn_k<<<dim3(32, 32), 256, 0, stream>>>(q, k, vt, y);
    gemm_k<1><<<dim3((MM / 128) * (1024 / 64)), 256, 0, stream>>>(
        y, Wt_proj, nullptr, nullptr, nullptr, out, 1024, 1024);
}